// Round 1
// baseline (1017.895 us; speedup 1.0000x reference)
//
#include <hip/hip_runtime.h>

// LaterallyConnectedLayer: B=16, NUM_FM=32, N_REPL=4, C=128, H=W=56, K_SZ=5
// Key algebraic facts used:
//  - softmax map sums to 1 -> first conv/softmax never affects winners -> skipped
//  - Am has only 32 nonzero channels per batch (winners) -> sparse K_change & conv
//  - all padding ops are pure index remaps; Ab stored zero-ring-padded [60][64]

#define EPSF 1e-10f

// pad_activations 60-map: pA[r] = Ab[map60(r)]
__device__ __forceinline__ int map60(int r) {
  return r < 4 ? 5 - r : (r < 56 ? r - 2 : 109 - r);
}

// k1: Abp[b][c][60][64] = zero-ring-padded relu(A_sym[b][c%32] + 0.1*noise[b][c]);
//     s[b*128+c] = sum over the 56x56 interior
__global__ __launch_bounds__(256) void k1_build(const float* __restrict__ A,
                                                const float* __restrict__ noise,
                                                float* __restrict__ Abp,
                                                float* __restrict__ s) {
  int bc = blockIdx.x;
  int b = bc >> 7, c = bc & 127;
  int fm = c & 31;
  const float* Abase = A + (size_t)(b * 32 + fm) * 3136;
  const float* nz = noise + (size_t)bc * 3136;
  float* outp = Abp + (size_t)bc * 3840;
  float local = 0.f;
  for (int idx = threadIdx.x; idx < 3840; idx += 256) {
    int r = idx >> 6, col = idx & 63;
    int h = r - 2, w = col - 2;
    float v = 0.f;
    if ((unsigned)h < 56u && (unsigned)w < 56u) {
      // symm_pad(A, 2) as index map (rows then cols is separable here)
      int hh = h < 2 ? 3 - h : (h >= 54 ? 107 - h : h);
      int ww = w < 2 ? 3 - w : (w >= 54 ? 107 - w : w);
      v = fmaxf(Abase[hh * 56 + ww] + 0.1f * nz[h * 56 + w], 0.f);
      local += v;
    }
    outp[idx] = v;
  }
  int lane = threadIdx.x & 63, wid = threadIdx.x >> 6;
  float v = local;
  for (int off = 32; off; off >>= 1) v += __shfl_down(v, off, 64);
  __shared__ float red[4];
  if (lane == 0) red[wid] = v;
  __syncthreads();
  if (threadIdx.x == 0) s[bc] = red[0] + red[1] + red[2] + red[3];
}

// k2: winners (argmax over 4 replicas, first-max tiebreak), fm_idx and per-channel
//     batch bitmask cmask[c]
__global__ __launch_bounds__(512) void k2_winners(const float* __restrict__ s,
                                                  int* __restrict__ fm_idx,
                                                  int* __restrict__ cmask) {
  int t = threadIdx.x;
  if (t < 512) {
    int b = t >> 5, f = t & 31;
    float best = s[b * 128 + f];
    int bn = 0;
    for (int n = 1; n < 4; n++) {
      float v = s[b * 128 + n * 32 + f];
      if (v > best) { best = v; bn = n; }
    }
    fm_idx[t] = bn * 32 + f;
  }
  __syncthreads();
  if (t < 128) {
    int m = 0;
    for (int b = 0; b < 16; b++)
      if (fm_idx[b * 32 + (t & 31)] == t) m |= (1 << b);
    cmask[t] = m;
  }
}

// k3: K_change[c][a][x][y] = (1/2048) * sum_{b in winners(c)} sum_{h,w}
//       Ab[b,c,h,w] * Abp[b,a,h+4-x, w+4-y]   (zero ring handles truncation)
__global__ __launch_bounds__(256) void k3_kchange(const float* __restrict__ Abp,
                                                  const int* __restrict__ cmask,
                                                  float* __restrict__ Kc) {
  int a = blockIdx.x, c = blockIdx.y;
  int mask = cmask[c];
  float acc[25];
#pragma unroll
  for (int t = 0; t < 25; t++) acc[t] = 0.f;
  for (int b = 0; b < 16; b++) {
    if (!((mask >> b) & 1)) continue;
    const float* pc = Abp + (size_t)(b * 128 + c) * 3840;
    const float* pa = Abp + (size_t)(b * 128 + a) * 3840;
    for (int q = threadIdx.x; q < 784; q += 256) {  // 56 rows x 14 quads
      int h = q / 14;
      int wq = (q - h * 14) * 4;
      const float* vc = pc + (h + 2) * 64 + wq + 2;
      float v0 = vc[0], v1 = vc[1], v2 = vc[2], v3 = vc[3];
#pragma unroll
      for (int xx = 0; xx < 5; xx++) {
        const float* row = pa + (h + xx) * 64 + wq;
        float r[8];
#pragma unroll
        for (int j = 0; j < 8; j++) r[j] = row[j];
#pragma unroll
        for (int yy = 0; yy < 5; yy++)
          acc[xx * 5 + yy] += v0 * r[yy] + v1 * r[yy + 1] + v2 * r[yy + 2] + v3 * r[yy + 3];
      }
    }
  }
  int lane = threadIdx.x & 63, wid = threadIdx.x >> 6;
  __shared__ float part[4][25];
#pragma unroll
  for (int t = 0; t < 25; t++) {
    float v = acc[t];
    for (int off = 32; off; off >>= 1) v += __shfl_down(v, off, 64);
    if (lane == 0) part[wid][t] = v;
  }
  __syncthreads();
  if (threadIdx.x < 25) {
    float v = part[0][threadIdx.x] + part[1][threadIdx.x] + part[2][threadIdx.x] +
              part[3][threadIdx.x];
    // acc index t'' = x''*5+y'' corresponds to K_change tap (4-x'',4-y'') = 24-t''
    Kc[((size_t)c * 128 + a) * 25 + (24 - threadIdx.x)] = v * (1.0f / 2048.0f);
  }
}

// k4: W2[o][i][t] = minmax25( 0.9*K[o][i][t] + 0.1*minmax25(Kc[i][o][.])[t] )
__global__ __launch_bounds__(256) void k4_weights(const float* __restrict__ Kc,
                                                  const float* __restrict__ K,
                                                  float* __restrict__ W2) {
  int gid = blockIdx.x * 256 + threadIdx.x;  // 16384 = 128*128
  int o = gid >> 7, i = gid & 127;
  const float* p = Kc + ((size_t)i * 128 + o) * 25;
  float kc[25], mn = 1e30f, mx = -1e30f;
#pragma unroll
  for (int t = 0; t < 25; t++) {
    kc[t] = p[t];
    mn = fminf(mn, kc[t]);
    mx = fmaxf(mx, kc[t]);
  }
  float d1 = mx - mn + EPSF;
  const float* kp = K + ((size_t)o * 128 + i) * 25;  // K1[i][o] = K[o][i]
  float k2[25], mn2 = 1e30f, mx2 = -1e30f;
#pragma unroll
  for (int t = 0; t < 25; t++) {
    k2[t] = 0.9f * kp[t] + 0.1f * ((kc[t] - mn) / d1);
    mn2 = fminf(mn2, k2[t]);
    mx2 = fmaxf(mx2, k2[t]);
  }
  float d2 = mx2 - mn2 + EPSF;
#pragma unroll
  for (int t = 0; t < 25; t++) W2[(size_t)gid * 25 + t] = (k2[t] - mn2) / d2;
}

// k5: O[b][f] = Ab[b][o] + (0.1/32) * sum_{g} conv5x5(pA2[b][winch[g]], W2[o][winch[g]])
//     where o = fm_idx[b][f]; pA2 staged in LDS via map60 remap of Abp
__global__ __launch_bounds__(256) void k5_out(const float* __restrict__ Abp,
                                             const float* __restrict__ W2,
                                             const int* __restrict__ fm_idx,
                                             float* __restrict__ O) {
  int bf = blockIdx.x;
  int b = bf >> 5;
  int o = fm_idx[bf];
  __shared__ float tile[3840];
  __shared__ float wsm[25];
  __shared__ int winch[32];
  if (threadIdx.x < 32) winch[threadIdx.x] = fm_idx[(b << 5) + threadIdx.x];
  int hk[13], wk[13];
  float acc[13];
#pragma unroll
  for (int k = 0; k < 13; k++) {
    acc[k] = 0.f;
    int p = threadIdx.x + (k << 8);
    hk[k] = p / 56;
    wk[k] = p - hk[k] * 56;
  }
  __syncthreads();
  for (int g = 0; g < 32; g++) {
    int i = winch[g];
    const float* src = Abp + (size_t)((b << 7) + i) * 3840;
    for (int idx = threadIdx.x; idx < 3840; idx += 256) {
      int r = idx >> 6, s2 = idx & 63;
      float v = 0.f;
      if (s2 < 60) v = src[(map60(r) + 2) * 64 + map60(s2) + 2];
      tile[idx] = v;
    }
    if (threadIdx.x < 25) wsm[threadIdx.x] = W2[(size_t)(o * 128 + i) * 25 + threadIdx.x];
    __syncthreads();
#pragma unroll
    for (int k = 0; k < 13; k++) {
      int p = threadIdx.x + (k << 8);
      if (p < 3136) {
        float sum = acc[k];
#pragma unroll
        for (int x = 0; x < 5; x++) {
          const float* tr = &tile[(hk[k] + x) * 64 + wk[k]];
#pragma unroll
          for (int y = 0; y < 5; y++) sum += wsm[x * 5 + y] * tr[y];
        }
        acc[k] = sum;
      }
    }
    __syncthreads();
  }
  const float* abo = Abp + (size_t)((b << 7) + o) * 3840;
  float* op = O + (size_t)bf * 3136;
#pragma unroll
  for (int k = 0; k < 13; k++) {
    int p = threadIdx.x + (k << 8);
    if (p < 3136) op[p] = abo[(hk[k] + 2) * 64 + wk[k] + 2] + acc[k] * (0.1f / 32.0f);
  }
}

extern "C" void kernel_launch(void* const* d_in, const int* in_sizes, int n_in,
                              void* d_out, int out_size, void* d_ws, size_t ws_size,
                              hipStream_t stream) {
  const float* A = (const float*)d_in[0];      // (16,32,56,56)
  const float* K = (const float*)d_in[1];      // (128,128,5,5) already softmaxed
  const float* noise = (const float*)d_in[2];  // (16,128,56,56)
  float* O = (float*)d_out;                    // (16,32,56,56)

  float* ws = (float*)d_ws;
  float* Abp = ws;                       // 16*128*60*64 = 7,864,320 floats
  float* s = ws + 7864320;               // 2048
  int* fm_idx = (int*)(ws + 7866368);    // 512
  int* cmask = (int*)(ws + 7866880);     // 128
  float* Kc = ws + 7867008;              // 128*128*25 = 409,600
  float* W2 = ws + 8276608;              // 409,600   (end: 8,686,208 floats ~ 34.7 MB)

  k1_build<<<2048, 256, 0, stream>>>(A, noise, Abp, s);
  k2_winners<<<1, 512, 0, stream>>>(s, fm_idx, cmask);
  k3_kchange<<<dim3(128, 128), 256, 0, stream>>>(Abp, cmask, Kc);
  k4_weights<<<64, 256, 0, stream>>>(Kc, K, W2);
  k5_out<<<512, 256, 0, stream>>>(Abp, W2, fm_idx, O);
}

// Round 2
// 350.206 us; speedup vs baseline: 2.9066x; 2.9066x over previous
//
#include <hip/hip_runtime.h>

// LaterallyConnectedLayer: B=16, NUM_FM=32, N_REPL=4, C=128, H=W=56, K_SZ=5
// Algebra used:
//  - softmax map sums to 1 -> first conv/softmax never affects winners -> skipped
//  - Am has only 32 nonzero channels per batch (winners) -> sparse K_change & conv
//  - padding ops are pure index remaps; Ab stored zero-ring-padded [60][64]
// R1: k3 -> block-per-(b,a), a-tile in LDS, thread-owns-g, 4x4 reg blocking;
//     k5 -> 4x4 reg blocking, b128 LDS reads, s_load weights, prebuilt pA2 (k2b).

#define EPSF 1e-10f

__device__ __forceinline__ int map60(int r) {
  return r < 4 ? 5 - r : (r < 56 ? r - 2 : 109 - r);
}

// k1: Abp[b][c][60][64] = zero-ring-padded relu(A_sym[b][c%32] + 0.1*noise[b][c]);
//     s[b*128+c] = interior sum
__global__ __launch_bounds__(256) void k1_build(const float* __restrict__ A,
                                                const float* __restrict__ noise,
                                                float* __restrict__ Abp,
                                                float* __restrict__ s) {
  int bc = blockIdx.x;
  int b = bc >> 7, c = bc & 127;
  int fm = c & 31;
  const float* Abase = A + (size_t)(b * 32 + fm) * 3136;
  const float* nz = noise + (size_t)bc * 3136;
  float* outp = Abp + (size_t)bc * 3840;
  float local = 0.f;
  for (int idx = threadIdx.x; idx < 3840; idx += 256) {
    int r = idx >> 6, col = idx & 63;
    int h = r - 2, w = col - 2;
    float v = 0.f;
    if ((unsigned)h < 56u && (unsigned)w < 56u) {
      int hh = h < 2 ? 3 - h : (h >= 54 ? 107 - h : h);
      int ww = w < 2 ? 3 - w : (w >= 54 ? 107 - w : w);
      v = fmaxf(Abase[hh * 56 + ww] + 0.1f * nz[h * 56 + w], 0.f);
      local += v;
    }
    outp[idx] = v;
  }
  int lane = threadIdx.x & 63, wid = threadIdx.x >> 6;
  float v = local;
  for (int off = 32; off; off >>= 1) v += __shfl_down(v, off, 64);
  __shared__ float red[4];
  if (lane == 0) red[wid] = v;
  __syncthreads();
  if (threadIdx.x == 0) s[bc] = red[0] + red[1] + red[2] + red[3];
}

// k2: winners + per-channel batch bitmask
__global__ __launch_bounds__(512) void k2_winners(const float* __restrict__ s,
                                                  int* __restrict__ fm_idx,
                                                  int* __restrict__ cmask) {
  int t = threadIdx.x;
  {
    int b = t >> 5, f = t & 31;
    float best = s[b * 128 + f];
    int bn = 0;
    for (int n = 1; n < 4; n++) {
      float v = s[b * 128 + n * 32 + f];
      if (v > best) { best = v; bn = n; }
    }
    fm_idx[t] = bn * 32 + f;
  }
  __syncthreads();
  if (t < 128) {
    int m = 0;
    for (int b = 0; b < 16; b++)
      if (fm_idx[b * 32 + (t & 31)] == t) m |= (1 << b);
    cmask[t] = m;
  }
}

// k2b: Abp2[b][g][60][64] = pad_activations(winner tile g of batch b), compact copy
__global__ __launch_bounds__(256) void k2b_pa2(const float* __restrict__ Abp,
                                               const int* __restrict__ fm_idx,
                                               float* __restrict__ Abp2) {
  int bg = blockIdx.x;  // 512 = 16*32
  int b = bg >> 5;
  int i = fm_idx[bg];
  const float* src = Abp + (size_t)(b * 128 + i) * 3840;
  float* dst = Abp2 + (size_t)bg * 3840;
  for (int idx = threadIdx.x; idx < 3840; idx += 256) {
    int r = idx >> 6, s2 = idx & 63;
    float v = 0.f;
    if (s2 < 60) v = src[(map60(r) + 2) * 64 + map60(s2) + 2];
    dst[idx] = v;
  }
}

// k3: per-b correlation. Block=(a,b). a-tile staged in LDS once; thread owns
//     (g = tid>>3, strip = tid&7); 4x4 center blocking; acc[25] per thread;
//     3-step shfl_xor reduce; write Kc_b[b][g][a][25] (tap-flipped, /2048).
__global__ __launch_bounds__(256) void k3_kchange(const float* __restrict__ Abp,
                                                  const int* __restrict__ fm_idx,
                                                  float* __restrict__ Kc_b) {
  int a = blockIdx.x, b = blockIdx.y;
  __shared__ __align__(16) float tile[3840];
  const float4* src4 = reinterpret_cast<const float4*>(Abp + (size_t)(b * 128 + a) * 3840);
  float4* t4 = reinterpret_cast<float4*>(tile);
  {
    int q = threadIdx.x;
    t4[q] = src4[q];
    t4[q + 256] = src4[q + 256];
    t4[q + 512] = src4[q + 512];
    if (q < 192) t4[q + 768] = src4[q + 768];
  }
  __syncthreads();
  int g = threadIdx.x >> 3, strip = threadIdx.x & 7;
  int c = fm_idx[b * 32 + g];
  const float* pc = Abp + (size_t)(b * 128 + c) * 3840;
  float acc[25];
#pragma unroll
  for (int t = 0; t < 25; t++) acc[t] = 0.f;

  for (int task = strip; task < 196; task += 8) {
    int rq = task / 14, wq = task - rq * 14;
    int h0 = rq * 4, w0 = wq * 4;
    float v[4][4];
#pragma unroll
    for (int hr = 0; hr < 4; hr++) {
      const float2* p2 = reinterpret_cast<const float2*>(pc + (h0 + hr + 2) * 64 + w0 + 2);
      float2 x0 = p2[0], x1 = p2[1];
      v[hr][0] = x0.x; v[hr][1] = x0.y; v[hr][2] = x1.x; v[hr][3] = x1.y;
    }
#pragma unroll
    for (int tr = 0; tr < 8; tr++) {
      const float4* rp = reinterpret_cast<const float4*>(tile + (h0 + tr) * 64 + w0);
      float4 ra = rp[0], rb = rp[1];
      float r[8] = {ra.x, ra.y, ra.z, ra.w, rb.x, rb.y, rb.z, rb.w};
#pragma unroll
      for (int hr = 0; hr < 4; hr++) {
        int xx = tr - hr;
        if (xx >= 0 && xx <= 4) {
#pragma unroll
          for (int yy = 0; yy < 5; yy++)
            acc[xx * 5 + yy] += v[hr][0] * r[yy] + v[hr][1] * r[yy + 1] +
                                v[hr][2] * r[yy + 2] + v[hr][3] * r[yy + 3];
        }
      }
    }
  }
#pragma unroll
  for (int t = 0; t < 25; t++) {
    float x = acc[t];
    x += __shfl_xor(x, 1, 64);
    x += __shfl_xor(x, 2, 64);
    x += __shfl_xor(x, 4, 64);
    acc[t] = x;
  }
  if (strip == 0) {
    float* out = Kc_b + (((size_t)b * 32 + g) * 128 + a) * 25;
#pragma unroll
    for (int t = 0; t < 25; t++) out[24 - t] = acc[t] * (1.0f / 2048.0f);
  }
}

// k4: W2[o][i][t] = minmax25( 0.9*K[o][i][t] + 0.1*minmax25(sum_b Kc_b[b][i&31][o][.]) )
__global__ __launch_bounds__(256) void k4_weights(const float* __restrict__ Kc_b,
                                                  const float* __restrict__ K,
                                                  const int* __restrict__ cmask,
                                                  float* __restrict__ W2) {
  int gid = blockIdx.x * 256 + threadIdx.x;  // 16384
  int o = gid >> 7, i = gid & 127;
  int m = cmask[i];
  float kc[25];
#pragma unroll
  for (int t = 0; t < 25; t++) kc[t] = 0.f;
  for (int b = 0; b < 16; b++) {
    if ((m >> b) & 1) {
      const float* p = Kc_b + (((size_t)b * 32 + (i & 31)) * 128 + o) * 25;
#pragma unroll
      for (int t = 0; t < 25; t++) kc[t] += p[t];
    }
  }
  float mn = 1e30f, mx = -1e30f;
#pragma unroll
  for (int t = 0; t < 25; t++) { mn = fminf(mn, kc[t]); mx = fmaxf(mx, kc[t]); }
  float d1 = mx - mn + EPSF;
  const float* kp = K + ((size_t)o * 128 + i) * 25;  // K1[i][o] = K[o][i]
  float k2[25], mn2 = 1e30f, mx2 = -1e30f;
#pragma unroll
  for (int t = 0; t < 25; t++) {
    k2[t] = 0.9f * kp[t] + 0.1f * ((kc[t] - mn) / d1);
    mn2 = fminf(mn2, k2[t]);
    mx2 = fmaxf(mx2, k2[t]);
  }
  float d2 = mx2 - mn2 + EPSF;
#pragma unroll
  for (int t = 0; t < 25; t++) W2[(size_t)gid * 25 + t] = (k2[t] - mn2) / d2;
}

// k5: O[b][f] = Ab[b][o] + (0.1/32) * sum_g conv5x5(Abp2[b][g], W2[o][winch[g]])
//     Block=(b,f); 4x4 blocking; tile float4-staged; weights via s_load.
__global__ __launch_bounds__(256) void k5_out(const float* __restrict__ Abp,
                                             const float* __restrict__ Abp2,
                                             const float* __restrict__ W2,
                                             const int* __restrict__ fm_idx,
                                             float* __restrict__ O) {
  int bf = blockIdx.x;
  int b = bf >> 5;
  int o = __builtin_amdgcn_readfirstlane(fm_idx[bf]);
  __shared__ __align__(16) float tile[3840];
  __shared__ int winch[32];
  if (threadIdx.x < 32) winch[threadIdx.x] = fm_idx[(b << 5) + threadIdx.x];
  int task = threadIdx.x;
  int rq = task / 14, wq = task - rq * 14;
  int h0 = rq * 4, w0 = wq * 4;
  float acc[4][4];
#pragma unroll
  for (int x = 0; x < 4; x++)
#pragma unroll
    for (int j = 0; j < 4; j++) acc[x][j] = 0.f;

  const float* base2 = Abp2 + (size_t)b * 32 * 3840;
  float4* t4 = reinterpret_cast<float4*>(tile);
  for (int g = 0; g < 32; g++) {
    __syncthreads();  // previous iteration's readers done
    const float4* s4 = reinterpret_cast<const float4*>(base2 + (size_t)g * 3840);
    {
      int q = threadIdx.x;
      t4[q] = s4[q];
      t4[q + 256] = s4[q + 256];
      t4[q + 512] = s4[q + 512];
      if (q < 192) t4[q + 768] = s4[q + 768];
    }
    int i = __builtin_amdgcn_readfirstlane(winch[g]);
    const float* wp = W2 + ((size_t)o * 128 + i) * 25;
    float w[25];
#pragma unroll
    for (int t = 0; t < 25; t++) w[t] = wp[t];
    __syncthreads();
    if (task < 196) {
#pragma unroll
      for (int tr = 0; tr < 8; tr++) {
        const float4* rp = reinterpret_cast<const float4*>(tile + (h0 + tr) * 64 + w0);
        float4 ra = rp[0], rb = rp[1];
        float r[8] = {ra.x, ra.y, ra.z, ra.w, rb.x, rb.y, rb.z, rb.w};
#pragma unroll
        for (int hr = 0; hr < 4; hr++) {
          int xx = tr - hr;
          if (xx >= 0 && xx <= 4) {
#pragma unroll
            for (int yy = 0; yy < 5; yy++)
              acc[hr][0] += w[xx * 5 + yy] * r[yy + 0],
              acc[hr][1] += w[xx * 5 + yy] * r[yy + 1],
              acc[hr][2] += w[xx * 5 + yy] * r[yy + 2],
              acc[hr][3] += w[xx * 5 + yy] * r[yy + 3];
          }
        }
      }
    }
  }
  if (task < 196) {
    const float* abo = Abp + (size_t)((b << 7) + o) * 3840;
    float* op = O + (size_t)bf * 3136;
#pragma unroll
    for (int hr = 0; hr < 4; hr++) {
      const float2* p2 = reinterpret_cast<const float2*>(abo + (h0 + hr + 2) * 64 + w0 + 2);
      float2 a0 = p2[0], a1 = p2[1];
      float4 out;
      out.x = a0.x + acc[hr][0] * (0.1f / 32.0f);
      out.y = a0.y + acc[hr][1] * (0.1f / 32.0f);
      out.z = a1.x + acc[hr][2] * (0.1f / 32.0f);
      out.w = a1.y + acc[hr][3] * (0.1f / 32.0f);
      *reinterpret_cast<float4*>(op + (h0 + hr) * 56 + w0) = out;
    }
  }
}

extern "C" void kernel_launch(void* const* d_in, const int* in_sizes, int n_in,
                              void* d_out, int out_size, void* d_ws, size_t ws_size,
                              hipStream_t stream) {
  const float* A = (const float*)d_in[0];
  const float* K = (const float*)d_in[1];
  const float* noise = (const float*)d_in[2];
  float* O = (float*)d_out;

  float* ws = (float*)d_ws;
  float* Abp = ws;                          // 7,864,320 floats
  float* Abp2 = ws + 7864320;               // 1,966,080
  float* s = ws + 9830400;                  // 2,048
  int* fm_idx = (int*)(ws + 9832448);       // 512
  int* cmask = (int*)(ws + 9832960);        // 128
  float* Kc_b = ws + 9833088;               // 1,638,400
  float* W2 = ws + 11471488;                // 409,600  (end 11,881,088 fl ~ 47.5 MB)

  k1_build<<<2048, 256, 0, stream>>>(A, noise, Abp, s);
  k2_winners<<<1, 512, 0, stream>>>(s, fm_idx, cmask);
  k2b_pa2<<<512, 256, 0, stream>>>(Abp, fm_idx, Abp2);
  k3_kchange<<<dim3(128, 16), 256, 0, stream>>>(Abp, fm_idx, Kc_b);
  k4_weights<<<64, 256, 0, stream>>>(Kc_b, K, cmask, W2);
  k5_out<<<512, 256, 0, stream>>>(Abp, Abp2, W2, fm_idx, O);
}

// Round 5
// 301.886 us; speedup vs baseline: 3.3718x; 1.1601x over previous
//
#include <hip/hip_runtime.h>

// LaterallyConnectedLayer: B=16, NUM_FM=32, N_REPL=4, C=128, H=W=56, K_SZ=5
// Algebra:
//  - softmax map sums to 1 -> first conv never affects winners -> skipped
//  - winner sparsity: K_change and final conv only touch 32 of 128 channels
//  - padding = index remaps; activations in zero-ring-padded [60][64] frames
// R4 (bisect): k3 = R1's PROVEN fp32 correlation (bf16-sourced loads);
//              k5 stays MFMA. Isolates the deterministic 0.203 bug.

typedef __attribute__((ext_vector_type(8))) short short8;
typedef __attribute__((ext_vector_type(4))) float floatx4;

#define EPSF 1e-10f

__device__ __forceinline__ int map60(int r) {
  return r < 4 ? 5 - r : (r < 56 ? r - 2 : 109 - r);
}
__device__ __forceinline__ unsigned short f2bf(float x) {
  unsigned int u = __float_as_uint(x);
  u += 0x7fff + ((u >> 16) & 1);
  return (unsigned short)(u >> 16);
}
__device__ __forceinline__ float bf2f(unsigned int h) {
  return __uint_as_float((h & 0xffffu) << 16);
}

// k1: Abf[128 + bc*3840 + p] = bf16 zero-ring relu(A_sym + 0.1*noise);
//     s[bc] = fp32 interior sum (pre-rounding)
__global__ __launch_bounds__(256) void k1_build(const float* __restrict__ A,
                                                const float* __restrict__ noise,
                                                unsigned short* __restrict__ Abf,
                                                float* __restrict__ s) {
  int bc = blockIdx.x;
  int b = bc >> 7, c = bc & 127;
  int fm = c & 31;
  const float* Abase = A + (size_t)(b * 32 + fm) * 3136;
  const float* nz = noise + (size_t)bc * 3136;
  unsigned short* outb = Abf + 128 + (size_t)bc * 3840;
  float local = 0.f;
  for (int idx = threadIdx.x; idx < 3840; idx += 256) {
    int r = idx >> 6, col = idx & 63;
    int h = r - 2, w = col - 2;
    float v = 0.f;
    if ((unsigned)h < 56u && (unsigned)w < 56u) {
      int hh = h < 2 ? 3 - h : (h >= 54 ? 107 - h : h);
      int ww = w < 2 ? 3 - w : (w >= 54 ? 107 - w : w);
      v = fmaxf(Abase[hh * 56 + ww] + 0.1f * nz[h * 56 + w], 0.f);
      local += v;
    }
    outb[idx] = f2bf(v);
  }
  int lane = threadIdx.x & 63, wid = threadIdx.x >> 6;
  float v = local;
  for (int off = 32; off; off >>= 1) v += __shfl_down(v, off, 64);
  __shared__ float red[4];
  if (lane == 0) red[wid] = v;
  __syncthreads();
  if (threadIdx.x == 0) s[bc] = red[0] + red[1] + red[2] + red[3];
}

// k2: winners + per-channel batch bitmask + zero Abf guard rings
__global__ __launch_bounds__(512) void k2_winners(const float* __restrict__ s,
                                                  int* __restrict__ fm_idx,
                                                  int* __restrict__ cmask,
                                                  unsigned short* __restrict__ Abf) {
  int t = threadIdx.x;
  {
    int b = t >> 5, f = t & 31;
    float best = s[b * 128 + f];
    int bn = 0;
    for (int n = 1; n < 4; n++) {
      float v = s[b * 128 + n * 32 + f];
      if (v > best) { best = v; bn = n; }
    }
    fm_idx[t] = bn * 32 + f;
  }
  if (t < 128) Abf[t] = 0;
  if (t >= 384) Abf[128 + 7864320 + (t - 384)] = 0;
  __syncthreads();
  if (t < 128) {
    int m = 0;
    for (int b = 0; b < 16; b++)
      if (fm_idx[b * 32 + (t & 31)] == t) m |= (1 << b);
    cmask[t] = m;
  }
}

// k2t: T[b][p][g] = pad_activations(winner g of b) in pixel-major layout
__global__ __launch_bounds__(256) void k2t_transpose(const unsigned short* __restrict__ Abf,
                                                     const int* __restrict__ fm_idx,
                                                     unsigned short* __restrict__ T) {
  __shared__ int win[32];
  int b = blockIdx.x / 15, chunk = blockIdx.x % 15;  // 240 blocks
  if (threadIdx.x < 32) win[threadIdx.x] = fm_idx[b * 32 + threadIdx.x];
  __syncthreads();
  int p = chunk * 256 + threadIdx.x;
  int r = p >> 6, s2 = p & 63;
  int mr = map60(r) + 2;
  int ms = (s2 < 60) ? map60(s2) + 2 : -1;
  unsigned int out[16];
#pragma unroll
  for (int gp = 0; gp < 16; gp++) {
    unsigned short v0 = 0, v1 = 0;
    if (ms >= 0) {
      v0 = Abf[128 + ((size_t)(b * 128) + win[2 * gp]) * 3840 + mr * 64 + ms];
      v1 = Abf[128 + ((size_t)(b * 128) + win[2 * gp + 1]) * 3840 + mr * 64 + ms];
    }
    out[gp] = (unsigned)v0 | ((unsigned)v1 << 16);
  }
  uint4* dst = reinterpret_cast<uint4*>(T + (size_t)b * 122880 + (size_t)p * 32);
#pragma unroll
  for (int q = 0; q < 4; q++) {
    uint4 u;
    u.x = out[4 * q]; u.y = out[4 * q + 1]; u.z = out[4 * q + 2]; u.w = out[4 * q + 3];
    dst[q] = u;
  }
}

// k3: PROVEN fp32 correlation (the 350µs-pass version), bf16-sourced.
//     Block=(a,b); a-tile bf16->fp32 in LDS; thread owns (g = tid>>3, strip);
//     4x4 center blocking; acc[25]; shfl_xor reduce; Kc_b[b][g][a][25].
__global__ __launch_bounds__(256) void k3_kchange(const unsigned short* __restrict__ Abf,
                                                  const int* __restrict__ fm_idx,
                                                  float* __restrict__ Kc_b) {
  int a = blockIdx.x, b = blockIdx.y;
  __shared__ __align__(16) float tile[3840];
  const unsigned short* srcA = Abf + 128 + (size_t)(b * 128 + a) * 3840;
  for (int q = threadIdx.x; q < 960; q += 256) {
    uint2 w = *reinterpret_cast<const uint2*>(srcA + q * 4);
    tile[q * 4 + 0] = bf2f(w.x);
    tile[q * 4 + 1] = bf2f(w.x >> 16);
    tile[q * 4 + 2] = bf2f(w.y);
    tile[q * 4 + 3] = bf2f(w.y >> 16);
  }
  __syncthreads();
  int g = threadIdx.x >> 3, strip = threadIdx.x & 7;
  int c = fm_idx[b * 32 + g];
  const unsigned short* pc = Abf + 128 + (size_t)(b * 128 + c) * 3840;
  float acc[25];
#pragma unroll
  for (int t = 0; t < 25; t++) acc[t] = 0.f;

  for (int task = strip; task < 196; task += 8) {
    int rq = task / 14, wq = task - rq * 14;
    int h0 = rq * 4, w0 = wq * 4;
    float v[4][4];
#pragma unroll
    for (int hr = 0; hr < 4; hr++) {
      const unsigned int* pu =
          reinterpret_cast<const unsigned int*>(pc + (h0 + hr + 2) * 64 + w0 + 2);
      unsigned int x0 = pu[0], x1 = pu[1];
      v[hr][0] = bf2f(x0); v[hr][1] = bf2f(x0 >> 16);
      v[hr][2] = bf2f(x1); v[hr][3] = bf2f(x1 >> 16);
    }
#pragma unroll
    for (int tr = 0; tr < 8; tr++) {
      const float4* rp = reinterpret_cast<const float4*>(tile + (h0 + tr) * 64 + w0);
      float4 ra = rp[0], rb = rp[1];
      float r[8] = {ra.x, ra.y, ra.z, ra.w, rb.x, rb.y, rb.z, rb.w};
#pragma unroll
      for (int hr = 0; hr < 4; hr++) {
        int xx = tr - hr;
        if (xx >= 0 && xx <= 4) {
#pragma unroll
          for (int yy = 0; yy < 5; yy++)
            acc[xx * 5 + yy] += v[hr][0] * r[yy] + v[hr][1] * r[yy + 1] +
                                v[hr][2] * r[yy + 2] + v[hr][3] * r[yy + 3];
        }
      }
    }
  }
#pragma unroll
  for (int t = 0; t < 25; t++) {
    float x = acc[t];
    x += __shfl_xor(x, 1, 64);
    x += __shfl_xor(x, 2, 64);
    x += __shfl_xor(x, 4, 64);
    acc[t] = x;
  }
  if (strip == 0) {
    float* out = Kc_b + (((size_t)b * 32 + g) * 128 + a) * 25;
#pragma unroll
    for (int t = 0; t < 25; t++) out[24 - t] = acc[t] * (1.0f / 2048.0f);
  }
}

// k4: W2[o][i][t] = minmax25(0.9*K[o][i][t] + 0.1*minmax25(sum_b Kc_b[b][i&31][o][.]))
__global__ __launch_bounds__(256) void k4_weights(const float* __restrict__ Kc_b,
                                                  const float* __restrict__ K,
                                                  const int* __restrict__ cmask,
                                                  float* __restrict__ W2) {
  int gid = blockIdx.x * 256 + threadIdx.x;  // 16384
  int o = gid >> 7, i = gid & 127;
  int m = cmask[i];
  float kc[25];
#pragma unroll
  for (int t = 0; t < 25; t++) kc[t] = 0.f;
  for (int b = 0; b < 16; b++) {
    if ((m >> b) & 1) {
      const float* p = Kc_b + (((size_t)b * 32 + (i & 31)) * 128 + o) * 25;
#pragma unroll
      for (int t = 0; t < 25; t++) kc[t] += p[t];
    }
  }
  float mn = 1e30f, mx = -1e30f;
#pragma unroll
  for (int t = 0; t < 25; t++) { mn = fminf(mn, kc[t]); mx = fmaxf(mx, kc[t]); }
  float d1 = mx - mn + EPSF;
  const float* kp = K + ((size_t)o * 128 + i) * 25;
  float k2[25], mn2 = 1e30f, mx2 = -1e30f;
#pragma unroll
  for (int t = 0; t < 25; t++) {
    k2[t] = 0.9f * kp[t] + 0.1f * ((kc[t] - mn) / d1);
    mn2 = fminf(mn2, k2[t]);
    mx2 = fmaxf(mx2, k2[t]);
  }
  float d2 = mx2 - mn2 + EPSF;
#pragma unroll
  for (int t = 0; t < 25; t++) W2[(size_t)gid * 25 + t] = (k2[t] - mn2) / d2;
}

// k4b: W2g[b][t][f][g] bf16 = W2[o_f][i_g][t] (per-batch winner gather)
__global__ __launch_bounds__(256) void k4b_gather(const float* __restrict__ W2,
                                                  const int* __restrict__ fm_idx,
                                                  unsigned short* __restrict__ W2g) {
  int tid = blockIdx.x * 256 + threadIdx.x;  // 16384
  int b = tid >> 10, f = (tid >> 5) & 31, g = tid & 31;
  int o = fm_idx[b * 32 + f], i = fm_idx[b * 32 + g];
  const float* src = W2 + ((size_t)o * 128 + i) * 25;
#pragma unroll
  for (int t = 0; t < 25; t++)
    W2g[((size_t)((b * 25 + t) * 32 + f) << 5) + g] = f2bf(src[t]);
}

// k5: MFMA conv + gather epilogue. Block = 1 wave = (b, mtile, rowgroup of 4).
__global__ __launch_bounds__(64) void k5_mfma(const unsigned short* __restrict__ W2g,
                                              const unsigned short* __restrict__ T,
                                              const unsigned short* __restrict__ Abf,
                                              const int* __restrict__ fm_idx,
                                              float* __restrict__ O) {
  int bx = blockIdx.x;  // 448 = b(16) x mt(2) x rg(14)
  int rg = bx % 14;
  int mtb = bx / 14;
  int mt = mtb & 1, b = mtb >> 1;
  int lane = threadIdx.x, al = lane & 15, quad = lane >> 4;
  int fm = mt * 16 + al;
  short8 afr[25];
#pragma unroll
  for (int t = 0; t < 25; t++)
    afr[t] = *reinterpret_cast<const short8*>(
        W2g + ((size_t)((b * 25 + t) * 32 + fm) << 5) + quad * 8);
  int orow[4];
#pragma unroll
  for (int r = 0; r < 4; r++) orow[r] = fm_idx[b * 32 + mt * 16 + quad * 4 + r];
  const unsigned short* Tb = T + (size_t)b * 122880;
  for (int rr = 0; rr < 4; rr++) {
    int row = 2 + rg * 4 + rr;
    for (int pair = 0; pair < 2; pair++) {
      int px0 = row * 64 + pair * 32 + al;
      floatx4 acca = (floatx4){0.f, 0.f, 0.f, 0.f};
      floatx4 accb = (floatx4){0.f, 0.f, 0.f, 0.f};
#pragma unroll
      for (int t = 0; t < 25; t++) {
        int off = (t / 5 - 2) * 64 + (t % 5) - 2;
        const short8* pb = reinterpret_cast<const short8*>(
            Tb + (ptrdiff_t)(px0 + off) * 32 + quad * 8);
        short8 b0 = pb[0];
        short8 b1 = pb[64];  // +16 px
        acca = __builtin_amdgcn_mfma_f32_16x16x32_bf16(afr[t], b0, acca, 0, 0, 0);
        accb = __builtin_amdgcn_mfma_f32_16x16x32_bf16(afr[t], b1, accb, 0, 0, 0);
      }
      int h = row - 2;
#pragma unroll
      for (int half = 0; half < 2; half++) {
        floatx4 acc = half ? accb : acca;
        int cc = pair * 32 + half * 16 + al;
        if (cc >= 2 && cc < 58) {
          int w = cc - 2;
          int px = row * 64 + cc;
#pragma unroll
          for (int r = 0; r < 4; r++) {
            int f = mt * 16 + quad * 4 + r;
            float base = bf2f(Abf[128 + (size_t)(b * 128 + orow[r]) * 3840 + px]);
            O[(size_t)(b * 32 + f) * 3136 + h * 56 + w] = base + acc[r] * (0.1f / 32.0f);
          }
        }
      }
    }
  }
}

extern "C" void kernel_launch(void* const* d_in, const int* in_sizes, int n_in,
                              void* d_out, int out_size, void* d_ws, size_t ws_size,
                              hipStream_t stream) {
  const float* A = (const float*)d_in[0];
  const float* K = (const float*)d_in[1];
  const float* noise = (const float*)d_in[2];
  float* O = (float*)d_out;

  float* ws = (float*)d_ws;
  unsigned short* Abf = (unsigned short*)ws;              // 7,864,576 us
  float* s = ws + 3932288;                                // 2,048
  int* fm_idx = (int*)(ws + 3934336);                     // 512
  int* cmask = (int*)(ws + 3934848);                      // 128
  float* Kc_b = ws + 3934976;                             // 1,638,400
  float* W2 = ws + 5573376;                               // 409,600
  unsigned short* W2g = (unsigned short*)(ws + 5982976);  // 409,600 us
  unsigned short* T = (unsigned short*)(ws + 6187776);    // 1,966,080 us
  // end: 7,170,816 floats = 28.7 MB (<< R1's known-good 47.5 MB)

  k1_build<<<2048, 256, 0, stream>>>(A, noise, Abf, s);
  k2_winners<<<1, 512, 0, stream>>>(s, fm_idx, cmask, Abf);
  k2t_transpose<<<240, 256, 0, stream>>>(Abf, fm_idx, T);
  k3_kchange<<<dim3(128, 16), 256, 0, stream>>>(Abf, fm_idx, Kc_b);
  k4_weights<<<64, 256, 0, stream>>>(Kc_b, K, cmask, W2);
  k4b_gather<<<64, 256, 0, stream>>>(W2, fm_idx, W2g);
  k5_mfma<<<448, 64, 0, stream>>>(W2g, T, Abf, fm_idx, O);
}